// Round 1
// baseline (1217.146 us; speedup 1.0000x reference)
//
#include <hip/hip_runtime.h>
#include <math.h>

#define Bsz 32
#define Nn 207
#define Tt 12
#define Cc 2
#define HORr 12
#define DIDd 64
#define Hh 128
#define NBb 3
#define CONCATk 2560
#define BN (Bsz*Nn)           // 6624
#define ROWS (BN*Cc)          // 13248
#define XSTRIDE (CONCATk*Cc)  // 5120

// ---------------- K1: time gates + h_in + level + zero f_acc ----------------
__global__ __launch_bounds__(128) void k_timegate(
    const float* __restrict__ hist, const float* __restrict__ tod,
    const float* __restrict__ emb,
    const float* __restrict__ w1, const float* __restrict__ b1,
    const float* __restrict__ w2, const float* __restrict__ b2,
    const float* __restrict__ w3, const float* __restrict__ b3,
    float* __restrict__ h_in, float* __restrict__ level,
    float* __restrict__ tgf, float* __restrict__ f_acc)
{
  int bn = blockIdx.x;
  int n = bn % Nn;
  __shared__ float s_in[76];
  __shared__ float s_tg[128];
  __shared__ float s_tgb[12];
  __shared__ float s_h[24];
  int tid = threadIdx.x;
  if (tid < 64) s_in[tid] = emb[n*64 + tid];
  else if (tid < 76) s_in[tid] = tod[bn*12 + (tid - 64)];
  __syncthreads();
  float acc = b1[tid];
#pragma unroll 4
  for (int k = 0; k < 76; ++k) acc = fmaf(s_in[k], w1[k*128 + tid], acc);
  s_tg[tid] = fmaxf(acc, 0.f);
  __syncthreads();
  if (tid < 24) {
    int j = tid % 12;
    const float* w = (tid < 12) ? w2 : w3;
    float a = (tid < 12) ? b2[j] : b3[j];
    for (int k = 0; k < 128; ++k) a = fmaf(s_tg[k], w[k*12 + j], a);
    if (tid < 12) tgf[bn*12 + j] = a;
    else s_tgb[j] = a;
  }
  __syncthreads();
  if (tid < 24) {
    int t = tid >> 1;
    float v = hist[bn*24 + tid] / (1.f + s_tgb[t]);
    h_in[bn*24 + tid] = v;
    s_h[tid] = v;
    f_acc[bn*24 + tid] = 0.f;
  }
  __syncthreads();
  if (tid < 2) {
    float m = s_h[tid];
    for (int t = 1; t < 12; ++t) m = fmaxf(m, s_h[t*2 + tid]);
    level[bn*2 + tid] = m;
  }
}

// ---------------- K2: dp[n,m] = exp(10 * <emb_n, emb_m>) ----------------
__global__ __launch_bounds__(256) void k_dp(const float* __restrict__ emb,
                                            float* __restrict__ dp)
{
  int n = blockIdx.x;
  __shared__ float e[64];
  int tid = threadIdx.x;
  if (tid < 64) e[tid] = emb[n*64 + tid];
  __syncthreads();
  if (tid < Nn) {
    float a = 0.f;
#pragma unroll 8
    for (int k = 0; k < 64; ++k) a = fmaf(e[k], emb[tid*64 + k], a);
    dp[n*Nn + tid] = expf(10.f * a);
  }
}

// ---------------- K3: build x = hist tensor, layout [bn][k][c] (in d_out) ----------------
__global__ __launch_bounds__(256) void k_build(
    const float* __restrict__ h_in, const float* __restrict__ level,
    const float* __restrict__ dp, const float* __restrict__ emb,
    float* __restrict__ x)
{
  int bn = blockIdx.x;
  int b = bn / Nn, n = bn % Nn;
  __shared__ float s_dp[Nn];
  int tid = threadIdx.x;
  for (int m = tid; m < Nn; m += 256) s_dp[m] = dp[n*Nn + m];
  __syncthreads();
  float lev0 = level[bn*2], lev1 = level[bn*2+1];
  float inv0 = 1.f/(lev0+1e-8f), inv1 = 1.f/(lev1+1e-8f);
  const float* hb = h_in + (size_t)b*Nn*24;
  float* xo = x + (size_t)bn*XSTRIDE;
  for (int p = tid; p < XSTRIDE; p += 256) {
    int c = p & 1;
    int k = p >> 1;
    float lev = c ? lev1 : lev0;
    float inv = c ? inv1 : inv0;
    float v;
    if (k < 12) {
      v = h_in[bn*24 + p] * inv;                       // history / (level+eps)
    } else if (k < 2496) {
      int q = p - 24;
      int m = q / 24;
      int off = q - m*24;                               // = t*2 + c
      v = fmaxf((hb[m*24 + off]*s_dp[m] - lev) * inv, 0.f);
    } else {
      v = emb[n*64 + (k - 2496)];
    }
    xo[p] = v;
  }
}

// ---------------- K4: fc0 GEMM: h = relu(x @ W + b), A from interleaved x ----------------
// tile 64 rows (32 bn) x 64 cols, BK=16
__global__ __launch_bounds__(256) void k_gemm_fc0(
    const float* __restrict__ x, const float* __restrict__ W,
    const float* __restrict__ bias, float* __restrict__ out)
{
  __shared__ float As[16][68];   // [k][row], padded stride for store-bank spread
  __shared__ float Bs[16][64];   // [k][j]
  int tid = threadIdx.x;
  int bn0 = blockIdx.x * 32;
  int j0 = blockIdx.y * 64;
  int ry = tid >> 4, tx = tid & 15;
  int a_bnl = tid >> 3, a_f4 = tid & 7;
  int b_kl = tid >> 4, b_j4 = tid & 15;
  const float* xa = x + (size_t)(bn0 + a_bnl)*XSTRIDE + a_f4*4;
  const float* wa = W + (size_t)b_kl*128 + j0 + b_j4*4;
  float acc[4][4] = {};
  for (int k0 = 0; k0 < CONCATk; k0 += 16) {
    float4 av = *(const float4*)(xa + (size_t)k0*2);
    float4 bv = *(const float4*)(wa + (size_t)k0*128);
    __syncthreads();
    As[a_f4*2+0][a_bnl*2+0] = av.x;
    As[a_f4*2+0][a_bnl*2+1] = av.y;
    As[a_f4*2+1][a_bnl*2+0] = av.z;
    As[a_f4*2+1][a_bnl*2+1] = av.w;
    *(float4*)&Bs[b_kl][b_j4*4] = bv;
    __syncthreads();
#pragma unroll
    for (int kl = 0; kl < 16; ++kl) {
      float4 a4 = *(const float4*)&As[kl][ry*4];
      float4 b4 = *(const float4*)&Bs[kl][tx*4];
      float aa[4] = {a4.x, a4.y, a4.z, a4.w};
      float bb[4] = {b4.x, b4.y, b4.z, b4.w};
#pragma unroll
      for (int i = 0; i < 4; ++i)
#pragma unroll
        for (int j = 0; j < 4; ++j)
          acc[i][j] = fmaf(aa[i], bb[j], acc[i][j]);
    }
  }
  int r0 = bn0*2 + ry*4;
#pragma unroll
  for (int i = 0; i < 4; ++i) {
    float4 o;
    o.x = fmaxf(acc[i][0] + bias[j0 + tx*4 + 0], 0.f);
    o.y = fmaxf(acc[i][1] + bias[j0 + tx*4 + 1], 0.f);
    o.z = fmaxf(acc[i][2] + bias[j0 + tx*4 + 2], 0.f);
    o.w = fmaxf(acc[i][3] + bias[j0 + tx*4 + 3], 0.f);
    *(float4*)(out + (size_t)(r0 + i)*128 + j0 + tx*4) = o;
  }
}

// ---------------- K5: H x H GEMM: out = relu(A @ W + b), dense A ----------------
__global__ __launch_bounds__(256) void k_gemm_h(
    const float* __restrict__ A, const float* __restrict__ W,
    const float* __restrict__ bias, float* __restrict__ out)
{
  __shared__ float As[16][68];
  __shared__ float Bs[16][64];
  int tid = threadIdx.x;
  int r0b = blockIdx.x * 64;
  int j0 = blockIdx.y * 64;
  int ry = tid >> 4, tx = tid & 15;
  int a_rl = tid >> 2, a_f4 = tid & 3;
  int b_kl = tid >> 4, b_j4 = tid & 15;
  float acc[4][4] = {};
  for (int k0 = 0; k0 < 128; k0 += 16) {
    float4 av = *(const float4*)(A + (size_t)(r0b + a_rl)*128 + k0 + a_f4*4);
    float4 bv = *(const float4*)(W + (size_t)(k0 + b_kl)*128 + j0 + b_j4*4);
    __syncthreads();
    As[a_f4*4+0][a_rl] = av.x;
    As[a_f4*4+1][a_rl] = av.y;
    As[a_f4*4+2][a_rl] = av.z;
    As[a_f4*4+3][a_rl] = av.w;
    *(float4*)&Bs[b_kl][b_j4*4] = bv;
    __syncthreads();
#pragma unroll
    for (int kl = 0; kl < 16; ++kl) {
      float4 a4 = *(const float4*)&As[kl][ry*4];
      float4 b4 = *(const float4*)&Bs[kl][tx*4];
      float aa[4] = {a4.x, a4.y, a4.z, a4.w};
      float bb[4] = {b4.x, b4.y, b4.z, b4.w};
#pragma unroll
      for (int i = 0; i < 4; ++i)
#pragma unroll
        for (int j = 0; j < 4; ++j)
          acc[i][j] = fmaf(aa[i], bb[j], acc[i][j]);
    }
  }
  int r0 = r0b + ry*4;
#pragma unroll
  for (int i = 0; i < 4; ++i) {
    float4 o;
    o.x = fmaxf(acc[i][0] + bias[j0 + tx*4 + 0], 0.f);
    o.y = fmaxf(acc[i][1] + bias[j0 + tx*4 + 1], 0.f);
    o.z = fmaxf(acc[i][2] + bias[j0 + tx*4 + 2], 0.f);
    o.w = fmaxf(acc[i][3] + bias[j0 + tx*4 + 3], 0.f);
    *(float4*)(out + (size_t)(r0 + i)*128 + j0 + tx*4) = o;
  }
}

// ---------------- K6: forecast GEMM (accumulate): f_acc += h @ FW + fb ----------------
__global__ __launch_bounds__(256) void k_fore(
    const float* __restrict__ h, const float* __restrict__ FW,
    const float* __restrict__ fb, float* __restrict__ f_acc)
{
  __shared__ float Hs[64][128];
  __shared__ float Fw[1536];
  __shared__ float Fb[12];
  int tid = threadIdx.x;
  int r0 = blockIdx.x * 64;
  for (int i = tid; i < 2048; i += 256) {
    int rl = i >> 5, f4 = i & 31;
    *(float4*)&Hs[rl][f4*4] = *(const float4*)(h + (size_t)(r0 + rl)*128 + f4*4);
  }
  for (int i = tid; i < 1536; i += 256) Fw[i] = FW[i];
  if (tid < 12) Fb[tid] = fb[tid];
  __syncthreads();
  for (int o = tid; o < 768; o += 256) {
    int rl = o / 12, t = o - (o/12)*12;
    float a = Fb[t];
#pragma unroll 8
    for (int j = 0; j < 128; ++j) a = fmaf(Hs[rl][j], Fw[j*12 + t], a);
    f_acc[(size_t)(r0 + rl)*12 + t] += a;
  }
}

// ---------------- K7: backcast GEMM, in-place: x = relu(x - (h @ BW + bb)) ----------------
// tile 32 rows (16 bn) x 128 k-cols
__global__ __launch_bounds__(256) void k_gemm_back(
    const float* __restrict__ h, const float* __restrict__ BW,
    const float* __restrict__ bb, float* __restrict__ x)
{
  __shared__ float Hs[32][36];    // [j][row]
  __shared__ float Bs[32][128];   // [j][k]
  int tid = threadIdx.x;
  int bn0 = blockIdx.x * 16;
  int r0 = bn0 * 2;
  int k0 = blockIdx.y * 128;
  int ry = tid >> 5, tx = tid & 31;   // ry 0..7 -> 4 rows each; tx 0..31 -> 4 cols each
  int h_rl = tid >> 3, h_f4 = tid & 7;
  int b_jl = tid >> 3, b_kf = tid & 7;
  float acc[4][4] = {};
  for (int j0 = 0; j0 < 128; j0 += 32) {
    float4 hv = *(const float4*)(h + (size_t)(r0 + h_rl)*128 + j0 + h_f4*4);
    const float* wrow = BW + (size_t)(j0 + b_jl)*CONCATk + k0 + b_kf*16;
    float4 w0 = *(const float4*)(wrow + 0);
    float4 w1 = *(const float4*)(wrow + 4);
    float4 w2 = *(const float4*)(wrow + 8);
    float4 w3 = *(const float4*)(wrow + 12);
    __syncthreads();
    Hs[h_f4*4+0][h_rl] = hv.x;
    Hs[h_f4*4+1][h_rl] = hv.y;
    Hs[h_f4*4+2][h_rl] = hv.z;
    Hs[h_f4*4+3][h_rl] = hv.w;
    *(float4*)&Bs[b_jl][b_kf*16 + 0]  = w0;
    *(float4*)&Bs[b_jl][b_kf*16 + 4]  = w1;
    *(float4*)&Bs[b_jl][b_kf*16 + 8]  = w2;
    *(float4*)&Bs[b_jl][b_kf*16 + 12] = w3;
    __syncthreads();
#pragma unroll
    for (int jl = 0; jl < 32; ++jl) {
      float4 a4 = *(const float4*)&Hs[jl][ry*4];
      float4 b4 = *(const float4*)&Bs[jl][tx*4];
      float aa[4] = {a4.x, a4.y, a4.z, a4.w};
      float bv[4] = {b4.x, b4.y, b4.z, b4.w};
#pragma unroll
      for (int i = 0; i < 4; ++i)
#pragma unroll
        for (int j = 0; j < 4; ++j)
          acc[i][j] = fmaf(aa[i], bv[j], acc[i][j]);
    }
  }
#pragma unroll
  for (int i = 0; i < 4; ++i) {
    int r = r0 + ry*4 + i;
    int bn = r >> 1, c = r & 1;
    float* xr = x + (size_t)bn*XSTRIDE + c;
#pragma unroll
    for (int j = 0; j < 4; ++j) {
      int k = k0 + tx*4 + j;
      float xv = xr[(size_t)k*2];
      xr[(size_t)k*2] = fmaxf(xv - (acc[i][j] + bb[k]), 0.f);
    }
  }
}

// ---------------- K8: finalize forecast ----------------
__global__ __launch_bounds__(256) void k_forecast(
    const float* __restrict__ f_acc, const float* __restrict__ level,
    const float* __restrict__ tgf, float* __restrict__ outf)
{
  int idx = blockIdx.x*256 + threadIdx.x;
  if (idx >= BN*24) return;
  int bn = idx / 24;
  int rem = idx - bn*24;
  int t = rem >> 1, c = rem & 1;
  float v = f_acc[bn*24 + c*12 + t];
  outf[idx] = v * level[bn*2 + c] * (1.f + tgf[bn*12 + t]);
}

extern "C" void kernel_launch(void* const* d_in, const int* in_sizes, int n_in,
                              void* d_out, int out_size, void* d_ws, size_t ws_size,
                              hipStream_t stream)
{
  const float* hist = (const float*)d_in[0];
  const float* tod  = (const float*)d_in[1];
  const float* emb  = (const float*)d_in[2];
  const float* tg1w = (const float*)d_in[3];
  const float* tg1b = (const float*)d_in[4];
  const float* tg2w = (const float*)d_in[5];
  const float* tg2b = (const float*)d_in[6];
  const float* tg3w = (const float*)d_in[7];
  const float* tg3b = (const float*)d_in[8];
  const float* fc0w = (const float*)d_in[9];
  const float* fc0b = (const float*)d_in[10];
  const float* fcw  = (const float*)d_in[11];
  const float* fcb  = (const float*)d_in[12];
  const float* forew= (const float*)d_in[13];
  const float* foreb= (const float*)d_in[14];
  const float* backw= (const float*)d_in[15];
  const float* backb= (const float*)d_in[16];

  float* ws    = (float*)d_ws;
  float* h_in  = ws;                    // 158976
  float* level = h_in + 158976;         // 13248
  float* tgf   = level + 13248;         // 79488
  float* dp    = tgf + 79488;           // 42849 (padded to 42852)
  float* f_acc = dp + 42852;            // 158976
  float* h0    = f_acc + 158976;        // 1695744
  float* h1    = h0 + 1695744;          // 1695744
  // x/backcast lives in d_out in final (b,n,k,c) layout; forecast after it.
  float* x    = (float*)d_out;
  float* outf = (float*)d_out + (size_t)BN*CONCATk*Cc;

  k_timegate<<<BN, 128, 0, stream>>>(hist, tod, emb, tg1w, tg1b, tg2w, tg2b,
                                     tg3w, tg3b, h_in, level, tgf, f_acc);
  k_dp<<<Nn, 256, 0, stream>>>(emb, dp);
  k_build<<<BN, 256, 0, stream>>>(h_in, level, dp, emb, x);
  for (int i = 0; i < NBb; ++i) {
    k_gemm_fc0<<<dim3(207,2), 256, 0, stream>>>(
        x, fc0w + (size_t)i*CONCATk*Hh, fc0b + i*Hh, h0);
    k_gemm_h<<<dim3(207,2), 256, 0, stream>>>(
        h0, fcw + (size_t)(i*2+0)*Hh*Hh, fcb + (i*2+0)*Hh, h1);
    k_gemm_h<<<dim3(207,2), 256, 0, stream>>>(
        h1, fcw + (size_t)(i*2+1)*Hh*Hh, fcb + (i*2+1)*Hh, h0);
    k_fore<<<207, 256, 0, stream>>>(
        h0, forew + (size_t)i*Hh*HORr, foreb + i*HORr, f_acc);
    k_gemm_back<<<dim3(414,20), 256, 0, stream>>>(
        h0, backw + (size_t)i*Hh*CONCATk, backb + (size_t)i*CONCATk, x);
  }
  k_forecast<<<(BN*24 + 255)/256, 256, 0, stream>>>(f_acc, level, tgf, outf);
}

// Round 2
// 671.257 us; speedup vs baseline: 1.8132x; 1.8132x over previous
//
#include <hip/hip_runtime.h>
#include <math.h>

#define Bsz 32
#define Nn 207
#define Tt 12
#define Cc 2
#define HORr 12
#define DIDd 64
#define Hh 128
#define NBb 3
#define CONCATk 2560
#define BN (Bsz*Nn)           // 6624
#define ROWS (BN*Cc)          // 13248 = 207*64
#define XSTRIDE (CONCATk*Cc)  // 5120

typedef unsigned short u16;
typedef __attribute__((ext_vector_type(8))) short bf16x8;
typedef __attribute__((ext_vector_type(4))) float f32x4;

__device__ inline u16 f2b(float f) {
  unsigned u = __builtin_bit_cast(unsigned, f);
  u += 0x7fffu + ((u >> 16) & 1u);          // RNE
  return (u16)(u >> 16);
}
__device__ inline float b2f(u16 b) {
  unsigned u = ((unsigned)b) << 16;
  return __builtin_bit_cast(float, u);
}
__device__ inline void gld16(const void* g, void* l) {
  __builtin_amdgcn_global_load_lds((const __attribute__((address_space(1))) void*)g,
                                   (__attribute__((address_space(3))) void*)l, 16, 0, 0);
}

// ---------------- K1: time gates + h_in + level + zero f_acc ----------------
__global__ __launch_bounds__(128) void k_timegate(
    const float* __restrict__ hist, const float* __restrict__ tod,
    const float* __restrict__ emb,
    const float* __restrict__ w1, const float* __restrict__ b1,
    const float* __restrict__ w2, const float* __restrict__ b2,
    const float* __restrict__ w3, const float* __restrict__ b3,
    float* __restrict__ h_in, float* __restrict__ level,
    float* __restrict__ tgf, float* __restrict__ f_acc)
{
  int bn = blockIdx.x;
  int n = bn % Nn;
  __shared__ float s_in[76];
  __shared__ float s_tg[128];
  __shared__ float s_tgb[12];
  __shared__ float s_h[24];
  int tid = threadIdx.x;
  if (tid < 64) s_in[tid] = emb[n*64 + tid];
  else if (tid < 76) s_in[tid] = tod[bn*12 + (tid - 64)];
  __syncthreads();
  float acc = b1[tid];
#pragma unroll 4
  for (int k = 0; k < 76; ++k) acc = fmaf(s_in[k], w1[k*128 + tid], acc);
  s_tg[tid] = fmaxf(acc, 0.f);
  __syncthreads();
  if (tid < 24) {
    int j = tid % 12;
    const float* w = (tid < 12) ? w2 : w3;
    float a = (tid < 12) ? b2[j] : b3[j];
    for (int k = 0; k < 128; ++k) a = fmaf(s_tg[k], w[k*12 + j], a);
    if (tid < 12) tgf[bn*12 + j] = a;
    else s_tgb[j] = a;
  }
  __syncthreads();
  if (tid < 24) {
    int t = tid >> 1;
    float v = hist[bn*24 + tid] / (1.f + s_tgb[t]);
    h_in[bn*24 + tid] = v;
    s_h[tid] = v;
    f_acc[bn*24 + tid] = 0.f;
  }
  __syncthreads();
  if (tid < 2) {
    float m = s_h[tid];
    for (int t = 1; t < 12; ++t) m = fmaxf(m, s_h[t*2 + tid]);
    level[bn*2 + tid] = m;
  }
}

// ---------------- K2: dp[n,m] = exp(10 * <emb_n, emb_m>) ----------------
__global__ __launch_bounds__(256) void k_dp(const float* __restrict__ emb,
                                            float* __restrict__ dp)
{
  int n = blockIdx.x;
  __shared__ float e[64];
  int tid = threadIdx.x;
  if (tid < 64) e[tid] = emb[n*64 + tid];
  __syncthreads();
  if (tid < Nn) {
    float a = 0.f;
#pragma unroll 8
    for (int k = 0; k < 64; ++k) a = fmaf(e[k], emb[tid*64 + k], a);
    dp[n*Nn + tid] = expf(10.f * a);
  }
}

// ---------------- weight conversion: fp32 [K][N] -> bf16 [N][K] ----------------
__global__ __launch_bounds__(256) void k_conv(
    const float* __restrict__ fc0w, const float* __restrict__ fcw,
    const float* __restrict__ backw,
    u16* __restrict__ fc0wt, u16* __restrict__ fcwt, u16* __restrict__ backwt)
{
  int g = blockIdx.x*256 + threadIdx.x;
  if (g < 3*128*2560) {
    int mat = g / (128*2560); int r = g - mat*(128*2560);
    int n = r / 2560, k = r - n*2560;
    fc0wt[g] = f2b(fc0w[(size_t)mat*2560*128 + (size_t)k*128 + n]);
    return;
  }
  g -= 3*128*2560;
  if (g < 6*128*128) {
    int mat = g >> 14; int r = g & 16383;
    int n = r >> 7, k = r & 127;
    fcwt[g] = f2b(fcw[(size_t)mat*16384 + k*128 + n]);
    return;
  }
  g -= 6*128*128;
  {
    int mat = g / (2560*128); int r = g - mat*(2560*128);
    int n = r >> 7, k = r & 127;
    backwt[g] = f2b(backw[(size_t)mat*128*2560 + (size_t)k*2560 + n]);
  }
}

// ---------------- K3a: build xb bf16, row-major [r=bn*2+c][k] ----------------
__global__ __launch_bounds__(256) void k_build_b(
    const float* __restrict__ h_in, const float* __restrict__ level,
    const float* __restrict__ dp, const float* __restrict__ emb,
    u16* __restrict__ xb)
{
  int bn = blockIdx.x;
  int b = bn / Nn, n = bn - b*Nn;
  __shared__ float s_dp[Nn];
  int tid = threadIdx.x;
  for (int m = tid; m < Nn; m += 256) s_dp[m] = dp[n*Nn + m];
  __syncthreads();
  float lev[2] = {level[bn*2], level[bn*2+1]};
  float inv[2] = {1.f/(lev[0]+1e-8f), 1.f/(lev[1]+1e-8f)};
  const float* hb = h_in + (size_t)b*Nn*24;
  for (int p = tid; p < 5120; p += 256) {
    int c = p / 2560, k = p - c*2560;
    float v;
    if (k < 12) v = h_in[bn*24 + k*2 + c] * inv[c];
    else if (k < 2496) {
      int q = k - 12; int m = q / 12, t = q - m*12;
      v = fmaxf((hb[m*24 + t*2 + c]*s_dp[m] - lev[c]) * inv[c], 0.f);
    } else v = emb[n*64 + (k - 2496)];
    xb[(size_t)(bn*2 + c)*2560 + k] = f2b(v);
  }
}

// ---------------- K3b: build x fp32, layout [bn][k][c] (fallback) ----------------
__global__ __launch_bounds__(256) void k_build_f(
    const float* __restrict__ h_in, const float* __restrict__ level,
    const float* __restrict__ dp, const float* __restrict__ emb,
    float* __restrict__ x)
{
  int bn = blockIdx.x;
  int b = bn / Nn, n = bn - b*Nn;
  __shared__ float s_dp[Nn];
  int tid = threadIdx.x;
  for (int m = tid; m < Nn; m += 256) s_dp[m] = dp[n*Nn + m];
  __syncthreads();
  float lev[2] = {level[bn*2], level[bn*2+1]};
  float inv[2] = {1.f/(lev[0]+1e-8f), 1.f/(lev[1]+1e-8f)};
  const float* hb = h_in + (size_t)b*Nn*24;
  float* xo = x + (size_t)bn*XSTRIDE;
  for (int p = tid; p < 5120; p += 256) {
    int c = p & 1, k = p >> 1;
    float v;
    if (k < 12) v = h_in[bn*24 + p] * inv[c];
    else if (k < 2496) {
      int q = k - 12; int m = q / 12, t = q - m*12;
      v = fmaxf((hb[m*24 + t*2 + c]*s_dp[m] - lev[c]) * inv[c], 0.f);
    } else v = emb[n*64 + (k - 2496)];
    xo[p] = v;
  }
}

// ---------------- MFMA GEMM, N=128: out = relu(A @ Bt^T + bias), bf16 out ----
// A bf16 row-major [M][K] (or fp32 interleaved x when AF32), Bt bf16 [128][K].
// 64x128 tile/block, 4 waves each 32x64. LDS chunk-major: slot = chunk*rows+row.
template<bool AF32>
__global__ __launch_bounds__(256) void k_mm_n128(
    const u16* __restrict__ A, const float* __restrict__ Xf, int K,
    const u16* __restrict__ Bt, const float* __restrict__ bias,
    u16* __restrict__ out)
{
  __shared__ u16 As[512*8];    // 8 chunks x 64 rows x 8 bf16
  __shared__ u16 Bs[1024*8];   // 8 chunks x 128 n x 8 bf16
  int tid = threadIdx.x;
  int r0 = blockIdx.x * 64;
  int wv = tid >> 6, lane = tid & 63;
  int m16 = lane & 15, quad = lane >> 4;
  int wr = (wv & 1) * 32, wc = (wv >> 1) * 64;
  int bn0 = r0 >> 1;
  f32x4 acc[2][4] = {};
  for (int k0 = 0; k0 < K; k0 += 64) {
    float4 xv0, xv1, xv2, xv3;
    if constexpr (AF32) {
      int bn_l = tid >> 3, kq = tid & 7;
      const float* xp = Xf + (size_t)(bn0 + bn_l)*XSTRIDE + (size_t)(k0 + kq*8)*2;
      xv0 = *(const float4*)(xp);
      xv1 = *(const float4*)(xp + 4);
      xv2 = *(const float4*)(xp + 8);
      xv3 = *(const float4*)(xp + 12);
    }
    __syncthreads();
    if constexpr (AF32) {
      int bn_l = tid >> 3, kq = tid & 7;
      u16 ra[8] = {f2b(xv0.x),f2b(xv0.z),f2b(xv1.x),f2b(xv1.z),
                   f2b(xv2.x),f2b(xv2.z),f2b(xv3.x),f2b(xv3.z)};
      u16 rb[8] = {f2b(xv0.y),f2b(xv0.w),f2b(xv1.y),f2b(xv1.w),
                   f2b(xv2.y),f2b(xv2.w),f2b(xv3.y),f2b(xv3.w)};
      *(bf16x8*)&As[(size_t)(kq*64 + bn_l*2 + 0)*8] = *(bf16x8*)ra;
      *(bf16x8*)&As[(size_t)(kq*64 + bn_l*2 + 1)*8] = *(bf16x8*)rb;
    } else {
#pragma unroll
      for (int it = 0; it < 2; ++it) {
        int slot = it*256 + tid;
        int chunk = slot >> 6, row = slot & 63;
        gld16(A + (size_t)(r0 + row)*K + k0 + chunk*8, &As[(size_t)(it*256 + wv*64)*8]);
      }
    }
#pragma unroll
    for (int it = 0; it < 4; ++it) {
      int slot = it*256 + tid;
      int chunk = slot >> 7, n = slot & 127;
      gld16(Bt + (size_t)n*K + k0 + chunk*8, &Bs[(size_t)(it*256 + wv*64)*8]);
    }
    __syncthreads();
#pragma unroll
    for (int ks = 0; ks < 2; ++ks) {
      int cb = ks*4 + quad;
      bf16x8 a0 = *(const bf16x8*)&As[(size_t)(cb*64 + wr + m16)*8];
      bf16x8 a1 = *(const bf16x8*)&As[(size_t)(cb*64 + wr + 16 + m16)*8];
      bf16x8 b0 = *(const bf16x8*)&Bs[(size_t)(cb*128 + wc + m16)*8];
      bf16x8 b1 = *(const bf16x8*)&Bs[(size_t)(cb*128 + wc + 16 + m16)*8];
      bf16x8 b2 = *(const bf16x8*)&Bs[(size_t)(cb*128 + wc + 32 + m16)*8];
      bf16x8 b3 = *(const bf16x8*)&Bs[(size_t)(cb*128 + wc + 48 + m16)*8];
      acc[0][0] = __builtin_amdgcn_mfma_f32_16x16x32_bf16(a0, b0, acc[0][0], 0, 0, 0);
      acc[0][1] = __builtin_amdgcn_mfma_f32_16x16x32_bf16(a0, b1, acc[0][1], 0, 0, 0);
      acc[0][2] = __builtin_amdgcn_mfma_f32_16x16x32_bf16(a0, b2, acc[0][2], 0, 0, 0);
      acc[0][3] = __builtin_amdgcn_mfma_f32_16x16x32_bf16(a0, b3, acc[0][3], 0, 0, 0);
      acc[1][0] = __builtin_amdgcn_mfma_f32_16x16x32_bf16(a1, b0, acc[1][0], 0, 0, 0);
      acc[1][1] = __builtin_amdgcn_mfma_f32_16x16x32_bf16(a1, b1, acc[1][1], 0, 0, 0);
      acc[1][2] = __builtin_amdgcn_mfma_f32_16x16x32_bf16(a1, b2, acc[1][2], 0, 0, 0);
      acc[1][3] = __builtin_amdgcn_mfma_f32_16x16x32_bf16(a1, b3, acc[1][3], 0, 0, 0);
    }
  }
#pragma unroll
  for (int i = 0; i < 2; ++i)
#pragma unroll
    for (int j = 0; j < 4; ++j) {
      int col = wc + j*16 + m16;
      float bsv = bias[col];
#pragma unroll
      for (int reg = 0; reg < 4; ++reg) {
        int row = r0 + wr + i*16 + quad*4 + reg;
        out[(size_t)row*128 + col] = f2b(fmaxf(acc[i][j][reg] + bsv, 0.f));
      }
    }
}

// ---------------- back GEMM: new_x = relu(x - (h @ BWt^T + bb)) ----------------
// MODE 0: xb bf16 in/out.  MODE 1: xb in, fp32 d_out [bn][k][c] out (final).
// MODE 2: fp32 x in d_out, in-place (fallback path).
template<int MODE>
__global__ __launch_bounds__(256) void k_back(
    const u16* __restrict__ h, const u16* __restrict__ Bt,
    const float* __restrict__ bb, u16* __restrict__ xb,
    float* __restrict__ xf)
{
  __shared__ u16 As[512*8];
  __shared__ u16 Bs[1024*8];
  int tid = threadIdx.x;
  int r0 = blockIdx.x * 64;
  int n0 = blockIdx.y * 128;
  int wv = tid >> 6, lane = tid & 63;
  int m16 = lane & 15, quad = lane >> 4;
  int wr = (wv & 1) * 32, wc = (wv >> 1) * 64;
  f32x4 acc[2][4] = {};
#pragma unroll
  for (int k0 = 0; k0 < 128; k0 += 64) {
    __syncthreads();
#pragma unroll
    for (int it = 0; it < 2; ++it) {
      int slot = it*256 + tid;
      int chunk = slot >> 6, row = slot & 63;
      gld16(h + (size_t)(r0 + row)*128 + k0 + chunk*8, &As[(size_t)(it*256 + wv*64)*8]);
    }
#pragma unroll
    for (int it = 0; it < 4; ++it) {
      int slot = it*256 + tid;
      int chunk = slot >> 7, n = slot & 127;
      gld16(Bt + (size_t)(n0 + n)*128 + k0 + chunk*8, &Bs[(size_t)(it*256 + wv*64)*8]);
    }
    __syncthreads();
#pragma unroll
    for (int ks = 0; ks < 2; ++ks) {
      int cb = ks*4 + quad;
      bf16x8 a0 = *(const bf16x8*)&As[(size_t)(cb*64 + wr + m16)*8];
      bf16x8 a1 = *(const bf16x8*)&As[(size_t)(cb*64 + wr + 16 + m16)*8];
      bf16x8 b0 = *(const bf16x8*)&Bs[(size_t)(cb*128 + wc + m16)*8];
      bf16x8 b1 = *(const bf16x8*)&Bs[(size_t)(cb*128 + wc + 16 + m16)*8];
      bf16x8 b2 = *(const bf16x8*)&Bs[(size_t)(cb*128 + wc + 32 + m16)*8];
      bf16x8 b3 = *(const bf16x8*)&Bs[(size_t)(cb*128 + wc + 48 + m16)*8];
      acc[0][0] = __builtin_amdgcn_mfma_f32_16x16x32_bf16(a0, b0, acc[0][0], 0, 0, 0);
      acc[0][1] = __builtin_amdgcn_mfma_f32_16x16x32_bf16(a0, b1, acc[0][1], 0, 0, 0);
      acc[0][2] = __builtin_amdgcn_mfma_f32_16x16x32_bf16(a0, b2, acc[0][2], 0, 0, 0);
      acc[0][3] = __builtin_amdgcn_mfma_f32_16x16x32_bf16(a0, b3, acc[0][3], 0, 0, 0);
      acc[1][0] = __builtin_amdgcn_mfma_f32_16x16x32_bf16(a1, b0, acc[1][0], 0, 0, 0);
      acc[1][1] = __builtin_amdgcn_mfma_f32_16x16x32_bf16(a1, b1, acc[1][1], 0, 0, 0);
      acc[1][2] = __builtin_amdgcn_mfma_f32_16x16x32_bf16(a1, b2, acc[1][2], 0, 0, 0);
      acc[1][3] = __builtin_amdgcn_mfma_f32_16x16x32_bf16(a1, b3, acc[1][3], 0, 0, 0);
    }
  }
#pragma unroll
  for (int i = 0; i < 2; ++i)
#pragma unroll
    for (int j = 0; j < 4; ++j) {
      int col = n0 + wc + j*16 + m16;
      float bsv = bb[col];
#pragma unroll
      for (int reg = 0; reg < 4; ++reg) {
        int row = r0 + wr + i*16 + quad*4 + reg;
        float v = acc[i][j][reg] + bsv;
        int bn = row >> 1, c = row & 1;
        if constexpr (MODE == 0) {
          size_t idx = (size_t)row*2560 + col;
          xb[idx] = f2b(fmaxf(b2f(xb[idx]) - v, 0.f));
        } else if constexpr (MODE == 1) {
          size_t idx = (size_t)row*2560 + col;
          xf[(size_t)bn*XSTRIDE + (size_t)col*2 + c] = fmaxf(b2f(xb[idx]) - v, 0.f);
        } else {
          size_t idx = (size_t)bn*XSTRIDE + (size_t)col*2 + c;
          xf[idx] = fmaxf(xf[idx] - v, 0.f);
        }
      }
    }
}

// ---------------- forecast GEMM (accumulate): f_acc += h @ FW + fb ------------
__global__ __launch_bounds__(256) void k_fore(
    const u16* __restrict__ h, const float* __restrict__ FW,
    const float* __restrict__ fb, float* __restrict__ f_acc)
{
  __shared__ float Hs[64][128];
  __shared__ float Fw[1536];
  __shared__ float Fb[12];
  int tid = threadIdx.x;
  int r0 = blockIdx.x * 64;
  for (int s = tid; s < 1024; s += 256) {
    int row = s >> 4, ch = s & 15;
    bf16x8 v = *(const bf16x8*)(h + (size_t)(r0 + row)*128 + ch*8);
#pragma unroll
    for (int j = 0; j < 8; ++j) Hs[row][ch*8 + j] = b2f((u16)v[j]);
  }
  for (int i = tid; i < 1536; i += 256) Fw[i] = FW[i];
  if (tid < 12) Fb[tid] = fb[tid];
  __syncthreads();
  for (int o = tid; o < 768; o += 256) {
    int rl = o / 12, t = o - (o/12)*12;
    float a = Fb[t];
#pragma unroll 8
    for (int j = 0; j < 128; ++j) a = fmaf(Hs[rl][j], Fw[j*12 + t], a);
    f_acc[(size_t)(r0 + rl)*12 + t] += a;
  }
}

// ---------------- finalize forecast ----------------
__global__ __launch_bounds__(256) void k_forecast(
    const float* __restrict__ f_acc, const float* __restrict__ level,
    const float* __restrict__ tgf, float* __restrict__ outf)
{
  int idx = blockIdx.x*256 + threadIdx.x;
  if (idx >= BN*24) return;
  int bn = idx / 24;
  int rem = idx - bn*24;
  int t = rem >> 1, c = rem & 1;
  float v = f_acc[bn*24 + c*12 + t];
  outf[idx] = v * level[bn*2 + c] * (1.f + tgf[bn*12 + t]);
}

extern "C" void kernel_launch(void* const* d_in, const int* in_sizes, int n_in,
                              void* d_out, int out_size, void* d_ws, size_t ws_size,
                              hipStream_t stream)
{
  const float* hist = (const float*)d_in[0];
  const float* tod  = (const float*)d_in[1];
  const float* emb  = (const float*)d_in[2];
  const float* tg1w = (const float*)d_in[3];
  const float* tg1b = (const float*)d_in[4];
  const float* tg2w = (const float*)d_in[5];
  const float* tg2b = (const float*)d_in[6];
  const float* tg3w = (const float*)d_in[7];
  const float* tg3b = (const float*)d_in[8];
  const float* fc0w = (const float*)d_in[9];
  const float* fc0b = (const float*)d_in[10];
  const float* fcw  = (const float*)d_in[11];
  const float* fcb  = (const float*)d_in[12];
  const float* forew= (const float*)d_in[13];
  const float* foreb= (const float*)d_in[14];
  const float* backw= (const float*)d_in[15];
  const float* backb= (const float*)d_in[16];

  char* w = (char*)d_ws;
  float* h_in  = (float*)w; w += 635904;     // 158976 f32
  float* level = (float*)w; w += 52992;      // 13248 f32
  float* tgf   = (float*)w; w += 317952;     // 79488 f32
  float* dp    = (float*)w; w += 171408;     // 42852 f32
  float* f_acc = (float*)w; w += 635904;     // 158976 f32
  u16* h0      = (u16*)w;   w += 3391488;    // 13248*128 bf16
  u16* h1      = (u16*)w;   w += 3391488;
  u16* fc0wt   = (u16*)w;   w += 1966080;    // 3 x [128][2560]
  u16* fcwt    = (u16*)w;   w += 196608;     // 6 x [128][128]
  u16* backwt  = (u16*)w;   w += 1966080;    // 3 x [2560][128]
  u16* xb      = (u16*)w;   w += 67829760;   // 13248*2560 bf16
  size_t need = (size_t)(w - (char*)d_ws);
  bool big = ws_size >= need;

  float* x    = (float*)d_out;                               // [bn][k][c] fp32
  float* outf = (float*)d_out + (size_t)BN*CONCATk*Cc;

  k_conv<<<8064, 256, 0, stream>>>(fc0w, fcw, backw, fc0wt, fcwt, backwt);
  k_timegate<<<BN, 128, 0, stream>>>(hist, tod, emb, tg1w, tg1b, tg2w, tg2b,
                                     tg3w, tg3b, h_in, level, tgf, f_acc);
  k_dp<<<Nn, 256, 0, stream>>>(emb, dp);
  if (big) k_build_b<<<BN, 256, 0, stream>>>(h_in, level, dp, emb, xb);
  else     k_build_f<<<BN, 256, 0, stream>>>(h_in, level, dp, emb, x);

  for (int i = 0; i < NBb; ++i) {
    if (big)
      k_mm_n128<false><<<207, 256, 0, stream>>>(
          xb, nullptr, 2560, fc0wt + (size_t)i*327680, fc0b + i*128, h0);
    else
      k_mm_n128<true><<<207, 256, 0, stream>>>(
          nullptr, x, 2560, fc0wt + (size_t)i*327680, fc0b + i*128, h0);
    k_mm_n128<false><<<207, 256, 0, stream>>>(
        h0, nullptr, 128, fcwt + (size_t)(i*2+0)*16384, fcb + (i*2+0)*128, h1);
    k_mm_n128<false><<<207, 256, 0, stream>>>(
        h1, nullptr, 128, fcwt + (size_t)(i*2+1)*16384, fcb + (i*2+1)*128, h0);
    k_fore<<<207, 256, 0, stream>>>(
        h0, forew + (size_t)i*Hh*HORr, foreb + i*HORr, f_acc);
    if (big) {
      if (i < NBb-1)
        k_back<0><<<dim3(207,20), 256, 0, stream>>>(
            h0, backwt + (size_t)i*327680, backb + (size_t)i*2560, xb, nullptr);
      else
        k_back<1><<<dim3(207,20), 256, 0, stream>>>(
            h0, backwt + (size_t)i*327680, backb + (size_t)i*2560, xb, x);
    } else {
      k_back<2><<<dim3(207,20), 256, 0, stream>>>(
          h0, backwt + (size_t)i*327680, backb + (size_t)i*2560, nullptr, x);
    }
  }
  k_forecast<<<(BN*24 + 255)/256, 256, 0, stream>>>(f_acc, level, tgf, outf);
}

// Round 3
// 557.431 us; speedup vs baseline: 2.1835x; 1.2042x over previous
//
#include <hip/hip_runtime.h>
#include <math.h>

#define Bsz 32
#define Nn 207
#define Tt 12
#define Cc 2
#define HORr 12
#define DIDd 64
#define Hh 128
#define NBb 3
#define CONCATk 2560
#define BN (Bsz*Nn)           // 6624
#define ROWS (BN*Cc)          // 13248 = 414*32
#define XSTRIDE (CONCATk*Cc)  // 5120

typedef unsigned short u16;
typedef __attribute__((ext_vector_type(8))) short bf16x8;
typedef __attribute__((ext_vector_type(4))) float f32x4;

__device__ inline u16 f2b(float f) {
  unsigned u = __builtin_bit_cast(unsigned, f);
  u += 0x7fffu + ((u >> 16) & 1u);          // RNE
  return (u16)(u >> 16);
}
__device__ inline float b2f(u16 b) {
  unsigned u = ((unsigned)b) << 16;
  return __builtin_bit_cast(float, u);
}
__device__ inline void gld16(const void* g, void* l) {
  __builtin_amdgcn_global_load_lds((const __attribute__((address_space(1))) void*)g,
                                   (__attribute__((address_space(3))) void*)l, 16, 0, 0);
}

// ---------------- K1: time gates + h_in + level + zero f_acc ----------------
__global__ __launch_bounds__(128) void k_timegate(
    const float* __restrict__ hist, const float* __restrict__ tod,
    const float* __restrict__ emb,
    const float* __restrict__ w1, const float* __restrict__ b1,
    const float* __restrict__ w2, const float* __restrict__ b2,
    const float* __restrict__ w3, const float* __restrict__ b3,
    float* __restrict__ h_in, float* __restrict__ level,
    float* __restrict__ tgf, float* __restrict__ f_acc)
{
  int bn = blockIdx.x;
  int n = bn % Nn;
  __shared__ float s_in[76];
  __shared__ float s_tg[128];
  __shared__ float s_tgb[12];
  __shared__ float s_h[24];
  int tid = threadIdx.x;
  if (tid < 64) s_in[tid] = emb[n*64 + tid];
  else if (tid < 76) s_in[tid] = tod[bn*12 + (tid - 64)];
  __syncthreads();
  float acc = b1[tid];
#pragma unroll 4
  for (int k = 0; k < 76; ++k) acc = fmaf(s_in[k], w1[k*128 + tid], acc);
  s_tg[tid] = fmaxf(acc, 0.f);
  __syncthreads();
  if (tid < 24) {
    int j = tid % 12;
    const float* w = (tid < 12) ? w2 : w3;
    float a = (tid < 12) ? b2[j] : b3[j];
    for (int k = 0; k < 128; ++k) a = fmaf(s_tg[k], w[k*12 + j], a);
    if (tid < 12) tgf[bn*12 + j] = a;
    else s_tgb[j] = a;
  }
  __syncthreads();
  if (tid < 24) {
    int t = tid >> 1;
    float v = hist[bn*24 + tid] / (1.f + s_tgb[t]);
    h_in[bn*24 + tid] = v;
    s_h[tid] = v;
    f_acc[bn*24 + tid] = 0.f;
  }
  __syncthreads();
  if (tid < 2) {
    float m = s_h[tid];
    for (int t = 1; t < 12; ++t) m = fmaxf(m, s_h[t*2 + tid]);
    level[bn*2 + tid] = m;
  }
}

// ---------------- K2: dp[n,m] = exp(10 * <emb_n, emb_m>) ----------------
__global__ __launch_bounds__(256) void k_dp(const float* __restrict__ emb,
                                            float* __restrict__ dp)
{
  int n = blockIdx.x;
  __shared__ float e[64];
  int tid = threadIdx.x;
  if (tid < 64) e[tid] = emb[n*64 + tid];
  __syncthreads();
  if (tid < Nn) {
    float a = 0.f;
#pragma unroll 8
    for (int k = 0; k < 64; ++k) a = fmaf(e[k], emb[tid*64 + k], a);
    dp[n*Nn + tid] = expf(10.f * a);
  }
}

// ---------------- weight transpose+convert: fp32 [K][N] -> bf16 [N][K] -------
// tiled 64x64 through LDS; grid (K/64, N/64, nmat)
__global__ __launch_bounds__(256) void k_transp(
    const float* __restrict__ src, u16* __restrict__ dst, int K, int N)
{
  int k0 = blockIdx.x*64, n0 = blockIdx.y*64;
  size_t mo = (size_t)blockIdx.z * K * N;
  src += mo; dst += mo;
  __shared__ u16 Ts[64][72];
  int tid = threadIdx.x;
#pragma unroll
  for (int it = 0; it < 4; ++it) {
    int idx = it*256 + tid;
    int r = idx >> 4, q = idx & 15;
    float4 v = *(const float4*)(src + (size_t)(k0 + r)*N + n0 + q*4);
    Ts[r][q*4+0] = f2b(v.x);
    Ts[r][q*4+1] = f2b(v.y);
    Ts[r][q*4+2] = f2b(v.z);
    Ts[r][q*4+3] = f2b(v.w);
  }
  __syncthreads();
#pragma unroll
  for (int it = 0; it < 2; ++it) {
    int idx = it*256 + tid;
    int nl = idx >> 3, kq = idx & 7;
    u16 o[8];
#pragma unroll
    for (int j = 0; j < 8; ++j) o[j] = Ts[kq*8 + j][nl];
    *(bf16x8*)(dst + (size_t)(n0 + nl)*K + k0 + kq*8) = *(bf16x8*)o;
  }
}

// ---------------- build xb bf16, row-major [r=bn*2+c][k], vectorized ---------
__global__ __launch_bounds__(256) void k_build_b(
    const float* __restrict__ h_in, const float* __restrict__ level,
    const float* __restrict__ dp, const float* __restrict__ emb,
    u16* __restrict__ xb)
{
  int bn = blockIdx.x;
  int b = bn / Nn, n = bn - b*Nn;
  __shared__ float s_dp[Nn];
  int tid = threadIdx.x;
  for (int m = tid; m < Nn; m += 256) s_dp[m] = dp[n*Nn + m];
  __syncthreads();
  float lev[2] = {level[bn*2], level[bn*2+1]};
  float inv[2] = {1.f/(lev[0]+1e-8f), 1.f/(lev[1]+1e-8f)};
  const float* hb = h_in + (size_t)b*Nn*24;
  for (int s = tid; s < 640; s += 256) {
    int c = s / 320, ks = s - c*320;
    u16 o[8];
#pragma unroll
    for (int j = 0; j < 8; ++j) {
      int k = ks*8 + j;
      float v;
      if (k < 12) v = h_in[bn*24 + k*2 + c] * inv[c];
      else if (k < 2496) {
        int q = k - 12; int m = q / 12, t = q - m*12;
        v = fmaxf((hb[m*24 + t*2 + c]*s_dp[m] - lev[c]) * inv[c], 0.f);
      } else v = emb[n*64 + (k - 2496)];
      o[j] = f2b(v);
    }
    *(bf16x8*)(xb + (size_t)(bn*2 + c)*2560 + ks*8) = *(bf16x8*)o;
  }
}

// ---------------- fused block kernel: fc0 -> h1 -> h2 -> h0out + fore_acc ----
// grid 414, block 256 (4 waves, wave tile 16 rows x 64 cols)
__global__ __launch_bounds__(256) void k_block(
    const u16* __restrict__ xb,
    const u16* __restrict__ W0t, const float* __restrict__ b0,
    const u16* __restrict__ W1t, const float* __restrict__ b1,
    const u16* __restrict__ W2t, const float* __restrict__ b2,
    const float* __restrict__ FW, const float* __restrict__ fb,
    u16* __restrict__ h0out, float* __restrict__ f_acc)
{
  __shared__ u16 As[2*256*8];    // 8KB: fc0 A dbuf; later Hs (32r x 16 chunks)
  __shared__ u16 Bs[2*1024*8];   // 32KB: fc0 B dbuf; later W (128n x 16 chunks)
  __shared__ float sFw[1536];
  __shared__ float sFb[12];
  const int tid = threadIdx.x, wv = tid >> 6, lane = tid & 63;
  const int m16 = lane & 15, quad = lane >> 4;
  const int wr = (wv & 1) * 16, wc = (wv >> 1) * 64;
  const int r0 = blockIdx.x * 32;

  // fc0 staging: A 32r x 8 chunks (256 slots), B 128n x 8 chunks (1024 slots)
  const int a_row = tid >> 3, a_c = tid & 7, a_g = a_c ^ (a_row & 7);
  const u16* a_src = xb + (size_t)(r0 + a_row)*2560 + a_g*8;
  u16* a_dst = &As[(wv*64)*8];
  const u16* b_src[4]; u16* b_dst[4];
#pragma unroll
  for (int it = 0; it < 4; ++it) {
    int slot = it*256 + tid;
    int nl = slot >> 3, c = slot & 7, g = c ^ (nl & 7);
    b_src[it] = W0t + (size_t)nl*2560 + g*8;
    b_dst[it] = &Bs[(it*256 + wv*64)*8];
  }
  // prologue: tile 0 -> buf 0
  gld16(a_src, a_dst);
#pragma unroll
  for (int it = 0; it < 4; ++it) gld16(b_src[it], b_dst[it]);

  f32x4 acc[4] = {};
  for (int i = 0; i < 40; ++i) {
    const int buf = i & 1;
    __syncthreads();
    if (i < 39) {
      const int nb = buf ^ 1;
      gld16(a_src + (i+1)*64, a_dst + nb*256*8);
#pragma unroll
      for (int it = 0; it < 4; ++it)
        gld16(b_src[it] + (i+1)*64, b_dst[it] + nb*1024*8);
    }
    const u16* Ab = &As[buf*256*8];
    const u16* Bb = &Bs[buf*1024*8];
#pragma unroll
    for (int ks = 0; ks < 2; ++ks) {
      int cb = ks*4 + quad;
      int arow = wr + m16;
      bf16x8 a = *(const bf16x8*)&Ab[(arow*8 + (cb ^ (arow & 7)))*8];
#pragma unroll
      for (int j = 0; j < 4; ++j) {
        int nl = wc + j*16 + m16;
        bf16x8 b = *(const bf16x8*)&Bb[(nl*8 + (cb ^ (nl & 7)))*8];
        acc[j] = __builtin_amdgcn_mfma_f32_16x16x32_bf16(a, b, acc[j], 0, 0, 0);
      }
    }
  }

  // helpers for the H x H phases (K=128, 16 chunks, XOR-15 swizzle)
  auto stageW = [&](const u16* W) {
#pragma unroll
    for (int it = 0; it < 8; ++it) {
      int slot = it*256 + tid;
      int nl = slot >> 4, c = slot & 15, g = c ^ (nl & 15);
      gld16(W + (size_t)nl*128 + g*8, &Bs[(it*256 + wv*64)*8]);
    }
  };
  auto writeH = [&](const f32x4* ac, const float* bias) {
#pragma unroll
    for (int j = 0; j < 4; ++j) {
      int col = wc + j*16 + m16;
      float bv = bias[col];
#pragma unroll
      for (int reg = 0; reg < 4; ++reg) {
        int row = wr + quad*4 + reg;
        int chunk = col >> 3;
        As[(row*16 + (chunk ^ (row & 15)))*8 + (col & 7)] =
            f2b(fmaxf(ac[j][reg] + bv, 0.f));
      }
    }
  };
  auto mm128 = [&](f32x4* ac) {
#pragma unroll
    for (int ks = 0; ks < 4; ++ks) {
      int cb = ks*4 + quad;
      int arow = wr + m16;
      bf16x8 a = *(const bf16x8*)&As[(arow*16 + (cb ^ (arow & 15)))*8];
#pragma unroll
      for (int j = 0; j < 4; ++j) {
        int nl = wc + j*16 + m16;
        bf16x8 b = *(const bf16x8*)&Bs[(nl*16 + (cb ^ (nl & 15)))*8];
        ac[j] = __builtin_amdgcn_mfma_f32_16x16x32_bf16(a, b, ac[j], 0, 0, 0);
      }
    }
  };

  __syncthreads();                 // all fc0 LDS reads done
  stageW(W1t);                     // W1 -> Bs
  for (int s = tid; s < 1536; s += 256) sFw[s] = FW[s];
  if (tid < 12) sFb[tid] = fb[tid];
  writeH(acc, b0);                 // h1 -> As
  __syncthreads();

  f32x4 acc2[4] = {};
  mm128(acc2);
  __syncthreads();
  stageW(W2t);                     // W2 -> Bs
  writeH(acc2, b1);                // h2 -> As
  __syncthreads();

  f32x4 acc3[4] = {};
  mm128(acc3);
  __syncthreads();
  writeH(acc3, b2);                // h3 -> As
  __syncthreads();

  // coop: h0out write (coalesced ushort8) + forecast accumulation
#pragma unroll
  for (int it = 0; it < 2; ++it) {
    int idx = it*256 + tid;
    int row = idx >> 4, cw = idx & 15;
    bf16x8 v = *(const bf16x8*)&As[(row*16 + (cw ^ (row & 15)))*8];
    *(bf16x8*)(h0out + (size_t)(r0 + row)*128 + cw*8) = v;
  }
  for (int o = tid; o < 384; o += 256) {
    int row = o / 12, t = o - (o/12)*12;
    float a = sFb[t];
#pragma unroll
    for (int chunk = 0; chunk < 16; ++chunk) {
      const u16* hp = &As[(row*16 + (chunk ^ (row & 15)))*8];
#pragma unroll
      for (int j = 0; j < 8; ++j)
        a = fmaf(b2f(hp[j]), sFw[(chunk*8 + j)*12 + t], a);
    }
    f_acc[(size_t)(r0 + row)*12 + t] += a;
  }
}

// ---------------- back GEMM: new_x = relu(x - (h @ BWt^T + bb)) --------------
// grid (414, 20), tile 32 rows x 128 n. MODE 0: xb bf16 in/out.
// MODE 1: xb in, fp32 d_out [bn][k][c] out (final block).
template<int MODE>
__global__ __launch_bounds__(256) void k_back2(
    const u16* __restrict__ h0, const u16* __restrict__ Bt,
    const float* __restrict__ bb, u16* __restrict__ xb,
    float* __restrict__ xf)
{
  __shared__ u16 Ah[512*8];      // 8KB
  __shared__ u16 Bw[2048*8];     // 32KB
  __shared__ float Cs[32*128];   // 16KB
  __shared__ float sBb[128];
  const int tid = threadIdx.x, wv = tid >> 6, lane = tid & 63;
  const int m16 = lane & 15, quad = lane >> 4;
  const int wr = (wv & 1) * 16, wc = (wv >> 1) * 64;
  const int r0 = blockIdx.x * 32, n0 = blockIdx.y * 128;

#pragma unroll
  for (int it = 0; it < 2; ++it) {
    int slot = it*256 + tid;
    int row = slot >> 4, c = slot & 15, g = c ^ (row & 15);
    gld16(h0 + (size_t)(r0 + row)*128 + g*8, &Ah[(it*256 + wv*64)*8]);
  }
#pragma unroll
  for (int it = 0; it < 8; ++it) {
    int slot = it*256 + tid;
    int nl = slot >> 4, c = slot & 15, g = c ^ (nl & 15);
    gld16(Bt + (size_t)(n0 + nl)*128 + g*8, &Bw[(it*256 + wv*64)*8]);
  }
  if (tid < 128) sBb[tid] = bb[n0 + tid];
  __syncthreads();

  f32x4 acc[4] = {};
#pragma unroll
  for (int ks = 0; ks < 4; ++ks) {
    int cb = ks*4 + quad;
    int arow = wr + m16;
    bf16x8 a = *(const bf16x8*)&Ah[(arow*16 + (cb ^ (arow & 15)))*8];
#pragma unroll
    for (int j = 0; j < 4; ++j) {
      int nl = wc + j*16 + m16;
      bf16x8 b = *(const bf16x8*)&Bw[(nl*16 + (cb ^ (nl & 15)))*8];
      acc[j] = __builtin_amdgcn_mfma_f32_16x16x32_bf16(a, b, acc[j], 0, 0, 0);
    }
  }
#pragma unroll
  for (int j = 0; j < 4; ++j) {
    int col = wc + j*16 + m16;
    float bv = sBb[col];
#pragma unroll
    for (int reg = 0; reg < 4; ++reg) {
      int row = wr + quad*4 + reg;
      Cs[row*128 + col] = acc[j][reg] + bv;
    }
  }
  __syncthreads();

  if constexpr (MODE == 0) {
#pragma unroll
    for (int it = 0; it < 2; ++it) {
      int idx = it*256 + tid;
      int row = idx >> 4, cw = idx & 15;
      u16* xp = xb + (size_t)(r0 + row)*2560 + n0 + cw*8;
      bf16x8 old = *(const bf16x8*)xp;
      u16 nv[8];
#pragma unroll
      for (int j = 0; j < 8; ++j)
        nv[j] = f2b(fmaxf(b2f((u16)old[j]) - Cs[row*128 + cw*8 + j], 0.f));
      *(bf16x8*)xp = *(bf16x8*)nv;
    }
  } else {
#pragma unroll
    for (int it = 0; it < 4; ++it) {
      int idx = it*256 + tid;
      int rp = idx >> 6, q = idx & 63;
      int lr0 = rp*2, lr1 = rp*2 + 1;
      const u16* x0 = xb + (size_t)(r0 + lr0)*2560 + n0 + q*2;
      const u16* x1 = xb + (size_t)(r0 + lr1)*2560 + n0 + q*2;
      float4 o;
      o.x = fmaxf(b2f(x0[0]) - Cs[lr0*128 + q*2 + 0], 0.f);
      o.y = fmaxf(b2f(x1[0]) - Cs[lr1*128 + q*2 + 0], 0.f);
      o.z = fmaxf(b2f(x0[1]) - Cs[lr0*128 + q*2 + 1], 0.f);
      o.w = fmaxf(b2f(x1[1]) - Cs[lr1*128 + q*2 + 1], 0.f);
      int bn = (r0 >> 1) + rp;
      *(float4*)(xf + (size_t)bn*XSTRIDE + (size_t)(n0 + q*2)*2) = o;
    }
  }
}

// ---------------- finalize forecast ----------------
__global__ __launch_bounds__(256) void k_forecast(
    const float* __restrict__ f_acc, const float* __restrict__ level,
    const float* __restrict__ tgf, float* __restrict__ outf)
{
  int idx = blockIdx.x*256 + threadIdx.x;
  if (idx >= BN*24) return;
  int bn = idx / 24;
  int rem = idx - bn*24;
  int t = rem >> 1, c = rem & 1;
  float v = f_acc[bn*24 + c*12 + t];
  outf[idx] = v * level[bn*2 + c] * (1.f + tgf[bn*12 + t]);
}

extern "C" void kernel_launch(void* const* d_in, const int* in_sizes, int n_in,
                              void* d_out, int out_size, void* d_ws, size_t ws_size,
                              hipStream_t stream)
{
  const float* hist = (const float*)d_in[0];
  const float* tod  = (const float*)d_in[1];
  const float* emb  = (const float*)d_in[2];
  const float* tg1w = (const float*)d_in[3];
  const float* tg1b = (const float*)d_in[4];
  const float* tg2w = (const float*)d_in[5];
  const float* tg2b = (const float*)d_in[6];
  const float* tg3w = (const float*)d_in[7];
  const float* tg3b = (const float*)d_in[8];
  const float* fc0w = (const float*)d_in[9];
  const float* fc0b = (const float*)d_in[10];
  const float* fcw  = (const float*)d_in[11];
  const float* fcb  = (const float*)d_in[12];
  const float* forew= (const float*)d_in[13];
  const float* foreb= (const float*)d_in[14];
  const float* backw= (const float*)d_in[15];
  const float* backb= (const float*)d_in[16];

  char* w = (char*)d_ws;
  float* h_in  = (float*)w; w += 635904;     // 158976 f32
  float* level = (float*)w; w += 52992;      // 13248 f32
  float* tgf   = (float*)w; w += 317952;     // 79488 f32
  float* dp    = (float*)w; w += 171408;     // 42852 f32
  float* f_acc = (float*)w; w += 635904;     // 158976 f32
  u16* h0      = (u16*)w;   w += 3391488;    // 13248*128 bf16
  u16* fc0wt   = (u16*)w;   w += 1966080;    // 3 x [128][2560]
  u16* fcwt    = (u16*)w;   w += 196608;     // 6 x [128][128]
  u16* backwt  = (u16*)w;   w += 1966080;    // 3 x [2560][128]
  u16* xb      = (u16*)w;   w += 67829760;   // 13248*2560 bf16

  float* x    = (float*)d_out;                               // [bn][k][c] fp32
  float* outf = (float*)d_out + (size_t)BN*CONCATk*Cc;

  k_transp<<<dim3(40, 2, 3), 256, 0, stream>>>(fc0w, fc0wt, 2560, 128);
  k_transp<<<dim3(2, 2, 6), 256, 0, stream>>>(fcw, fcwt, 128, 128);
  k_transp<<<dim3(2, 40, 3), 256, 0, stream>>>(backw, backwt, 128, 2560);
  k_timegate<<<BN, 128, 0, stream>>>(hist, tod, emb, tg1w, tg1b, tg2w, tg2b,
                                     tg3w, tg3b, h_in, level, tgf, f_acc);
  k_dp<<<Nn, 256, 0, stream>>>(emb, dp);
  k_build_b<<<BN, 256, 0, stream>>>(h_in, level, dp, emb, xb);

  for (int i = 0; i < NBb; ++i) {
    k_block<<<414, 256, 0, stream>>>(
        xb,
        fc0wt + (size_t)i*327680, fc0b + i*128,
        fcwt + (size_t)(i*2+0)*16384, fcb + (i*2+0)*128,
        fcwt + (size_t)(i*2+1)*16384, fcb + (i*2+1)*128,
        forew + (size_t)i*1536, foreb + i*12,
        h0, f_acc);
    if (i < NBb-1)
      k_back2<0><<<dim3(414, 20), 256, 0, stream>>>(
          h0, backwt + (size_t)i*327680, backb + (size_t)i*2560, xb, nullptr);
    else
      k_back2<1><<<dim3(414, 20), 256, 0, stream>>>(
          h0, backwt + (size_t)i*327680, backb + (size_t)i*2560, xb, x);
  }
  k_forecast<<<(BN*24 + 255)/256, 256, 0, stream>>>(f_acc, level, tgf, outf);
}

// Round 4
// 547.218 us; speedup vs baseline: 2.2242x; 1.0187x over previous
//
#include <hip/hip_runtime.h>
#include <math.h>

#define Bsz 32
#define Nn 207
#define Tt 12
#define Cc 2
#define HORr 12
#define DIDd 64
#define Hh 128
#define NBb 3
#define CONCATk 2560
#define BN (Bsz*Nn)           // 6624
#define ROWS (BN*Cc)          // 13248 = 414*32
#define XSTRIDE (CONCATk*Cc)  // 5120

typedef unsigned short u16;
typedef __attribute__((ext_vector_type(8))) short bf16x8;
typedef __attribute__((ext_vector_type(4))) float f32x4;

__device__ inline u16 f2b(float f) {
  unsigned u = __builtin_bit_cast(unsigned, f);
  u += 0x7fffu + ((u >> 16) & 1u);          // RNE
  return (u16)(u >> 16);
}
__device__ inline float b2f(u16 b) {
  unsigned u = ((unsigned)b) << 16;
  return __builtin_bit_cast(float, u);
}
__device__ inline void gld16(const void* g, void* l) {
  __builtin_amdgcn_global_load_lds((const __attribute__((address_space(1))) void*)g,
                                   (__attribute__((address_space(3))) void*)l, 16, 0, 0);
}

// ---------------- K1: time gates + h_in + level + zero f_acc ----------------
__global__ __launch_bounds__(128) void k_timegate(
    const float* __restrict__ hist, const float* __restrict__ tod,
    const float* __restrict__ emb,
    const float* __restrict__ w1, const float* __restrict__ b1,
    const float* __restrict__ w2, const float* __restrict__ b2,
    const float* __restrict__ w3, const float* __restrict__ b3,
    float* __restrict__ h_in, float* __restrict__ level,
    float* __restrict__ tgf, float* __restrict__ f_acc)
{
  int bn = blockIdx.x;
  int n = bn % Nn;
  __shared__ float s_in[76];
  __shared__ float s_tg[128];
  __shared__ float s_tgb[12];
  __shared__ float s_h[24];
  int tid = threadIdx.x;
  if (tid < 64) s_in[tid] = emb[n*64 + tid];
  else if (tid < 76) s_in[tid] = tod[bn*12 + (tid - 64)];
  __syncthreads();
  float acc = b1[tid];
#pragma unroll 4
  for (int k = 0; k < 76; ++k) acc = fmaf(s_in[k], w1[k*128 + tid], acc);
  s_tg[tid] = fmaxf(acc, 0.f);
  __syncthreads();
  if (tid < 24) {
    int j = tid % 12;
    const float* w = (tid < 12) ? w2 : w3;
    float a = (tid < 12) ? b2[j] : b3[j];
    for (int k = 0; k < 128; ++k) a = fmaf(s_tg[k], w[k*12 + j], a);
    if (tid < 12) tgf[bn*12 + j] = a;
    else s_tgb[j] = a;
  }
  __syncthreads();
  if (tid < 24) {
    int t = tid >> 1;
    float v = hist[bn*24 + tid] / (1.f + s_tgb[t]);
    h_in[bn*24 + tid] = v;
    s_h[tid] = v;
    f_acc[bn*24 + tid] = 0.f;
  }
  __syncthreads();
  if (tid < 2) {
    float m = s_h[tid];
    for (int t = 1; t < 12; ++t) m = fmaxf(m, s_h[t*2 + tid]);
    level[bn*2 + tid] = m;
  }
}

// ---------------- K2: dp[n,m] = exp(10 * <emb_n, emb_m>) ----------------
__global__ __launch_bounds__(256) void k_dp(const float* __restrict__ emb,
                                            float* __restrict__ dp)
{
  int n = blockIdx.x;
  __shared__ float e[64];
  int tid = threadIdx.x;
  if (tid < 64) e[tid] = emb[n*64 + tid];
  __syncthreads();
  if (tid < Nn) {
    float a = 0.f;
#pragma unroll 8
    for (int k = 0; k < 64; ++k) a = fmaf(e[k], emb[tid*64 + k], a);
    dp[n*Nn + tid] = expf(10.f * a);
  }
}

// ---------------- weight transpose+convert: fp32 [K][N] -> bf16 [N][K] -------
__global__ __launch_bounds__(256) void k_transp(
    const float* __restrict__ src, u16* __restrict__ dst, int K, int N)
{
  int k0 = blockIdx.x*64, n0 = blockIdx.y*64;
  size_t mo = (size_t)blockIdx.z * K * N;
  src += mo; dst += mo;
  __shared__ u16 Ts[64][72];
  int tid = threadIdx.x;
#pragma unroll
  for (int it = 0; it < 4; ++it) {
    int idx = it*256 + tid;
    int r = idx >> 4, q = idx & 15;
    float4 v = *(const float4*)(src + (size_t)(k0 + r)*N + n0 + q*4);
    Ts[r][q*4+0] = f2b(v.x);
    Ts[r][q*4+1] = f2b(v.y);
    Ts[r][q*4+2] = f2b(v.z);
    Ts[r][q*4+3] = f2b(v.w);
  }
  __syncthreads();
#pragma unroll
  for (int it = 0; it < 2; ++it) {
    int idx = it*256 + tid;
    int nl = idx >> 3, kq = idx & 7;
    u16 o[8];
#pragma unroll
    for (int j = 0; j < 8; ++j) o[j] = Ts[kq*8 + j][nl];
    *(bf16x8*)(dst + (size_t)(n0 + nl)*K + k0 + kq*8) = *(bf16x8*)o;
  }
}

// ---------------- build xb bf16, row-major [r=bn*2+c][k] ---------------------
__global__ __launch_bounds__(256) void k_build_b(
    const float* __restrict__ h_in, const float* __restrict__ level,
    const float* __restrict__ dp, const float* __restrict__ emb,
    u16* __restrict__ xb)
{
  int bn = blockIdx.x;
  int b = bn / Nn, n = bn - b*Nn;
  __shared__ float s_dp[Nn];
  int tid = threadIdx.x;
  for (int m = tid; m < Nn; m += 256) s_dp[m] = dp[n*Nn + m];
  __syncthreads();
  float lev[2] = {level[bn*2], level[bn*2+1]};
  float inv[2] = {1.f/(lev[0]+1e-8f), 1.f/(lev[1]+1e-8f)};
  const float* hb = h_in + (size_t)b*Nn*24;
  for (int s = tid; s < 640; s += 256) {
    int c = s / 320, ks = s - c*320;
    u16 o[8];
#pragma unroll
    for (int j = 0; j < 8; ++j) {
      int k = ks*8 + j;
      float v;
      if (k < 12) v = h_in[bn*24 + k*2 + c] * inv[c];
      else if (k < 2496) {
        int q = k - 12; int m = q / 12, t = q - m*12;
        v = fmaxf((hb[m*24 + t*2 + c]*s_dp[m] - lev[c]) * inv[c], 0.f);
      } else v = emb[n*64 + (k - 2496)];
      o[j] = f2b(v);
    }
    *(bf16x8*)(xb + (size_t)(bn*2 + c)*2560 + ks*8) = *(bf16x8*)o;
  }
}

// ---------------- fused N-BEATS block: fc0->h1->h2->h3 + fore + back ---------
// grid 414, block 256 (4 waves, wave tile 16 rows x 64 cols).
// FINAL=0: RMW xb (bf16). FINAL=1: write fp32 d_out [bn][k][c].
template<int FINAL>
__global__ __launch_bounds__(256) void k_mega(
    u16* __restrict__ xb,
    const u16* __restrict__ W0t, const float* __restrict__ b0,
    const u16* __restrict__ W1t, const float* __restrict__ b1,
    const u16* __restrict__ W2t, const float* __restrict__ b2,
    const float* __restrict__ FW, const float* __restrict__ fb,
    const u16* __restrict__ BWt, const float* __restrict__ bbias,
    float* __restrict__ f_acc, float* __restrict__ xf)
{
  __shared__ u16 As[2*256*8];    // 8KB: fc0 A dbuf; later h (32r x 16 chunks)
  __shared__ u16 Bs[2*1024*8];   // 32KB: fc0 B dbuf; later W1/W2/BW tiles
  __shared__ float Cs[32*132];   // 16.9KB, padded stride vs bank conflicts
  __shared__ float sFw[1536];
  __shared__ float sFb[12];
  __shared__ float sBb[128];
  const int tid = threadIdx.x, wv = tid >> 6, lane = tid & 63;
  const int m16 = lane & 15, quad = lane >> 4;
  const int wr = (wv & 1) * 16, wc = (wv >> 1) * 64;
  const int r0 = blockIdx.x * 32;

  // ---- phase 1: fc0, K=2560, BK=64, double-buffered ----
  const int a_row = tid >> 3, a_c = tid & 7, a_g = a_c ^ (a_row & 7);
  const u16* a_src = xb + (size_t)(r0 + a_row)*2560 + a_g*8;
  u16* a_dst = &As[(wv*64)*8];
  const u16* b_src[4]; u16* b_dst[4];
#pragma unroll
  for (int it = 0; it < 4; ++it) {
    int slot = it*256 + tid;
    int nl = slot >> 3, c = slot & 7, g = c ^ (nl & 7);
    b_src[it] = W0t + (size_t)nl*2560 + g*8;
    b_dst[it] = &Bs[(it*256 + wv*64)*8];
  }
  gld16(a_src, a_dst);
#pragma unroll
  for (int it = 0; it < 4; ++it) gld16(b_src[it], b_dst[it]);

  f32x4 acc[4] = {};
  for (int i = 0; i < 40; ++i) {
    const int buf = i & 1;
    __syncthreads();
    if (i < 39) {
      const int nb = buf ^ 1;
      gld16(a_src + (i+1)*64, a_dst + nb*256*8);
#pragma unroll
      for (int it = 0; it < 4; ++it)
        gld16(b_src[it] + (i+1)*64, b_dst[it] + nb*1024*8);
    }
    const u16* Ab = &As[buf*256*8];
    const u16* Bb = &Bs[buf*1024*8];
#pragma unroll
    for (int ks = 0; ks < 2; ++ks) {
      int cb = ks*4 + quad;
      int arow = wr + m16;
      bf16x8 a = *(const bf16x8*)&Ab[(arow*8 + (cb ^ (arow & 7)))*8];
#pragma unroll
      for (int j = 0; j < 4; ++j) {
        int nl = wc + j*16 + m16;
        bf16x8 b = *(const bf16x8*)&Bb[(nl*8 + (cb ^ (nl & 7)))*8];
        acc[j] = __builtin_amdgcn_mfma_f32_16x16x32_bf16(a, b, acc[j], 0, 0, 0);
      }
    }
  }

  // helpers for H x H phases (K=128, 16 chunks, XOR-15 swizzle)
  auto stageW = [&](const u16* W) {
#pragma unroll
    for (int it = 0; it < 8; ++it) {
      int slot = it*256 + tid;
      int nl = slot >> 4, c = slot & 15, g = c ^ (nl & 15);
      gld16(W + (size_t)nl*128 + g*8, &Bs[(it*256 + wv*64)*8]);
    }
  };
  auto writeH = [&](const f32x4* ac, const float* bias) {
#pragma unroll
    for (int j = 0; j < 4; ++j) {
      int col = wc + j*16 + m16;
      float bv = bias[col];
#pragma unroll
      for (int reg = 0; reg < 4; ++reg) {
        int row = wr + quad*4 + reg;
        int chunk = col >> 3;
        As[(row*16 + (chunk ^ (row & 15)))*8 + (col & 7)] =
            f2b(fmaxf(ac[j][reg] + bv, 0.f));
      }
    }
  };
  auto mm128 = [&](f32x4* ac) {
#pragma unroll
    for (int ks = 0; ks < 4; ++ks) {
      int cb = ks*4 + quad;
      int arow = wr + m16;
      bf16x8 a = *(const bf16x8*)&As[(arow*16 + (cb ^ (arow & 15)))*8];
#pragma unroll
      for (int j = 0; j < 4; ++j) {
        int nl = wc + j*16 + m16;
        bf16x8 b = *(const bf16x8*)&Bs[(nl*16 + (cb ^ (nl & 15)))*8];
        ac[j] = __builtin_amdgcn_mfma_f32_16x16x32_bf16(a, b, ac[j], 0, 0, 0);
      }
    }
  };

  __syncthreads();                 // fc0 LDS reads done
  stageW(W1t);
  for (int s = tid; s < 1536; s += 256) sFw[s] = FW[s];
  if (tid < 12) sFb[tid] = fb[tid];
  writeH(acc, b0);                 // h1 -> As
  __syncthreads();

  f32x4 acc2[4] = {};
  mm128(acc2);
  __syncthreads();
  stageW(W2t);
  writeH(acc2, b1);                // h2 -> As
  __syncthreads();

  f32x4 acc3[4] = {};
  mm128(acc3);
  __syncthreads();
  writeH(acc3, b2);                // h3 -> As (stays for back phase)
  __syncthreads();

  // forecast accumulation from As(h3)
  for (int o = tid; o < 384; o += 256) {
    int row = o / 12, t = o - (o/12)*12;
    float a = sFb[t];
#pragma unroll
    for (int chunk = 0; chunk < 16; ++chunk) {
      const u16* hp = &As[(row*16 + (chunk ^ (row & 15)))*8];
#pragma unroll
      for (int j = 0; j < 8; ++j)
        a = fmaf(b2f(hp[j]), sFw[(chunk*8 + j)*12 + t], a);
    }
    f_acc[(size_t)(r0 + row)*12 + t] += a;
  }

  // ---- phase 5: back GEMM over 20 column tiles of 128 ----
  for (int nt = 0; nt < 20; ++nt) {
    const int n0 = nt*128;
    __syncthreads();               // Bs/Cs free for reuse
#pragma unroll
    for (int it = 0; it < 8; ++it) {
      int slot = it*256 + tid;
      int nl = slot >> 4, c = slot & 15, g = c ^ (nl & 15);
      gld16(BWt + (size_t)(n0 + nl)*128 + g*8, &Bs[(it*256 + wv*64)*8]);
    }
    if (tid < 128) sBb[tid] = bbias[n0 + tid];
    __syncthreads();
    f32x4 bacc[4] = {};
#pragma unroll
    for (int ks = 0; ks < 4; ++ks) {
      int cb = ks*4 + quad;
      int arow = wr + m16;
      bf16x8 a = *(const bf16x8*)&As[(arow*16 + (cb ^ (arow & 15)))*8];
#pragma unroll
      for (int j = 0; j < 4; ++j) {
        int nl = wc + j*16 + m16;
        bf16x8 b = *(const bf16x8*)&Bs[(nl*16 + (cb ^ (nl & 15)))*8];
        bacc[j] = __builtin_amdgcn_mfma_f32_16x16x32_bf16(a, b, bacc[j], 0, 0, 0);
      }
    }
#pragma unroll
    for (int j = 0; j < 4; ++j) {
      int col = wc + j*16 + m16;
      float bv = sBb[col];
#pragma unroll
      for (int reg = 0; reg < 4; ++reg) {
        int row = wr + quad*4 + reg;
        Cs[row*132 + col] = bacc[j][reg] + bv;
      }
    }
    __syncthreads();
    if constexpr (!FINAL) {
#pragma unroll
      for (int it = 0; it < 2; ++it) {
        int idx = it*256 + tid;
        int row = idx >> 4, cw = idx & 15;
        u16* xp = xb + (size_t)(r0 + row)*2560 + n0 + cw*8;
        bf16x8 old = *(const bf16x8*)xp;
        u16 nv[8];
#pragma unroll
        for (int j = 0; j < 8; ++j)
          nv[j] = f2b(fmaxf(b2f((u16)old[j]) - Cs[row*132 + cw*8 + j], 0.f));
        *(bf16x8*)xp = *(bf16x8*)nv;
      }
    } else {
#pragma unroll
      for (int it = 0; it < 4; ++it) {
        int idx = it*256 + tid;
        int rp = idx >> 6, q = idx & 63;
        int lr0 = rp*2, lr1 = rp*2 + 1;
        const u16* x0 = xb + (size_t)(r0 + lr0)*2560 + n0 + q*2;
        const u16* x1 = xb + (size_t)(r0 + lr1)*2560 + n0 + q*2;
        float4 o;
        o.x = fmaxf(b2f(x0[0]) - Cs[lr0*132 + q*2 + 0], 0.f);
        o.y = fmaxf(b2f(x1[0]) - Cs[lr1*132 + q*2 + 0], 0.f);
        o.z = fmaxf(b2f(x0[1]) - Cs[lr0*132 + q*2 + 1], 0.f);
        o.w = fmaxf(b2f(x1[1]) - Cs[lr1*132 + q*2 + 1], 0.f);
        int bn = (r0 >> 1) + rp;
        *(float4*)(xf + (size_t)bn*XSTRIDE + (size_t)(n0 + q*2)*2) = o;
      }
    }
  }
}

// ---------------- finalize forecast ----------------
__global__ __launch_bounds__(256) void k_forecast(
    const float* __restrict__ f_acc, const float* __restrict__ level,
    const float* __restrict__ tgf, float* __restrict__ outf)
{
  int idx = blockIdx.x*256 + threadIdx.x;
  if (idx >= BN*24) return;
  int bn = idx / 24;
  int rem = idx - bn*24;
  int t = rem >> 1, c = rem & 1;
  float v = f_acc[bn*24 + c*12 + t];
  outf[idx] = v * level[bn*2 + c] * (1.f + tgf[bn*12 + t]);
}

extern "C" void kernel_launch(void* const* d_in, const int* in_sizes, int n_in,
                              void* d_out, int out_size, void* d_ws, size_t ws_size,
                              hipStream_t stream)
{
  const float* hist = (const float*)d_in[0];
  const float* tod  = (const float*)d_in[1];
  const float* emb  = (const float*)d_in[2];
  const float* tg1w = (const float*)d_in[3];
  const float* tg1b = (const float*)d_in[4];
  const float* tg2w = (const float*)d_in[5];
  const float* tg2b = (const float*)d_in[6];
  const float* tg3w = (const float*)d_in[7];
  const float* tg3b = (const float*)d_in[8];
  const float* fc0w = (const float*)d_in[9];
  const float* fc0b = (const float*)d_in[10];
  const float* fcw  = (const float*)d_in[11];
  const float* fcb  = (const float*)d_in[12];
  const float* forew= (const float*)d_in[13];
  const float* foreb= (const float*)d_in[14];
  const float* backw= (const float*)d_in[15];
  const float* backb= (const float*)d_in[16];

  char* w = (char*)d_ws;
  float* h_in  = (float*)w; w += 635904;     // 158976 f32
  float* level = (float*)w; w += 52992;      // 13248 f32
  float* tgf   = (float*)w; w += 317952;     // 79488 f32
  float* dp    = (float*)w; w += 171408;     // 42852 f32
  float* f_acc = (float*)w; w += 635904;     // 158976 f32
  u16* fc0wt   = (u16*)w;   w += 1966080;    // 3 x [128][2560]
  u16* fcwt    = (u16*)w;   w += 196608;     // 6 x [128][128]
  u16* backwt  = (u16*)w;   w += 1966080;    // 3 x [2560][128]
  u16* xb      = (u16*)w;   w += 67829760;   // 13248*2560 bf16

  float* x    = (float*)d_out;                               // [bn][k][c] fp32
  float* outf = (float*)d_out + (size_t)BN*CONCATk*Cc;

  k_transp<<<dim3(40, 2, 3), 256, 0, stream>>>(fc0w, fc0wt, 2560, 128);
  k_transp<<<dim3(2, 2, 6), 256, 0, stream>>>(fcw, fcwt, 128, 128);
  k_transp<<<dim3(2, 40, 3), 256, 0, stream>>>(backw, backwt, 128, 2560);
  k_timegate<<<BN, 128, 0, stream>>>(hist, tod, emb, tg1w, tg1b, tg2w, tg2b,
                                     tg3w, tg3b, h_in, level, tgf, f_acc);
  k_dp<<<Nn, 256, 0, stream>>>(emb, dp);
  k_build_b<<<BN, 256, 0, stream>>>(h_in, level, dp, emb, xb);

  for (int i = 0; i < NBb; ++i) {
    const u16* W0t = fc0wt + (size_t)i*327680;
    const u16* W1t = fcwt + (size_t)(i*2+0)*16384;
    const u16* W2t = fcwt + (size_t)(i*2+1)*16384;
    const u16* BWt = backwt + (size_t)i*327680;
    if (i < NBb-1)
      k_mega<0><<<414, 256, 0, stream>>>(
          xb, W0t, fc0b + i*128, W1t, fcb + (i*2+0)*128, W2t, fcb + (i*2+1)*128,
          forew + (size_t)i*1536, foreb + i*12, BWt, backb + (size_t)i*2560,
          f_acc, nullptr);
    else
      k_mega<1><<<414, 256, 0, stream>>>(
          xb, W0t, fc0b + i*128, W1t, fcb + (i*2+0)*128, W2t, fcb + (i*2+1)*128,
          forew + (size_t)i*1536, foreb + i*12, BWt, backb + (size_t)i*2560,
          f_acc, x);
  }
  k_forecast<<<(BN*24 + 255)/256, 256, 0, stream>>>(f_acc, level, tgf, outf);
}